// Round 1
// baseline (2082.246 us; speedup 1.0000x reference)
//
#include <hip/hip_runtime.h>
#include <hip/hip_bf16.h>
#include <math.h>

#define B_ 8
#define N_ 8192
#define E_ 16384
#define D_ 128
#define R_ 200
#define M_ 20
#define L_ 3
#define KEFF 384   // comp(128) + h_src(128) + conf(128); dist_src/h_r folded into tables
#define TE 16      // edges (or rows) per block

// ---------------- h init: h = dist_table[clip(dists)] + 0.1*noise ----------------
__global__ __launch_bounds__(256) void k_init_h(const int* __restrict__ dists,
    const float* __restrict__ noise, const float* __restrict__ dist_table,
    float* __restrict__ h) {
  int i = blockIdx.x * 256 + threadIdx.x;   // float4 index, total B*N*D/4
  int row = i >> 5;                          // D/4 = 32 float4 per row
  int d4 = i & 31;
  int dc = dists[row]; dc = dc < 0 ? 0 : (dc > 9 ? 9 : dc);
  const float4 t = *(const float4*)&dist_table[dc * D_ + d4 * 4];
  const float4 nz = *(const float4*)&noise[(size_t)i * 4];
  float4 o;
  o.x = t.x + 0.1f * nz.x; o.y = t.y + 0.1f * nz.y;
  o.z = t.z + 0.1f * nz.z; o.w = t.w + 0.1f * nz.w;
  *(float4*)&h[(size_t)i * 4] = o;
}

// ---------------- active-edge compaction (wave-aggregated atomic) ----------------
__global__ __launch_bounds__(256) void k_compact(const int* __restrict__ edge_mask,
    int* __restrict__ count, int* __restrict__ list) {
  int i = blockIdx.x * 256 + threadIdx.x;
  bool act = edge_mask[i] != 0;
  unsigned long long m = __ballot(act);
  int lane = threadIdx.x & 63;
  int base = 0;
  if (lane == 0) base = atomicAdd(count, __popcll(m));
  base = __shfl(base, 0);
  if (act) list[base + __popcll(m & ((1ull << lane) - 1ull))] = i;  // i = b*E+e
}

// ------- precompute T3b[k][t][d] = dist_table[t]@W3[k] + msg_b[k],  T4[k][r][d] = rel_table[r]@W4[k]
__global__ __launch_bounds__(128) void k_tables(const float* __restrict__ dist_table,
    const float* __restrict__ rel_table, const float* __restrict__ msg_W,
    const float* __restrict__ msg_b, float* __restrict__ T3b, float* __restrict__ T4) {
  int k = blockIdx.x / 210;
  int r = blockIdx.x % 210;
  int d = threadIdx.x;
  if (r < 10) {
    float acc = msg_b[k * D_ + d];
    for (int f = 0; f < D_; ++f)
      acc = fmaf(dist_table[r * D_ + f], msg_W[(size_t)(k * 640 + 256 + f) * D_ + d], acc);
    T3b[(k * 10 + r) * D_ + d] = acc;
  } else {
    int rr = r - 10;
    float acc = 0.f;
    for (int f = 0; f < D_; ++f)
      acc = fmaf(rel_table[rr * D_ + f], msg_W[(size_t)(k * 640 + 384 + f) * D_ + d], acc);
    T4[(k * R_ + rr) * D_ + d] = acc;
  }
}

// ------- transpose effective msg_W to [k][d][fe] (fe: 0:128 comp, 128:256 h_src, 256:384 conf)
__global__ __launch_bounds__(256) void k_wt_msg(const float* __restrict__ msg_W,
    float* __restrict__ Wt) {
  int idx = blockIdx.x * 256 + threadIdx.x;     // total L*D*KEFF
  int fe = idx % KEFF;
  int kd = idx / KEFF;
  int d = kd % D_;
  int k = kd / D_;
  int row = fe < 256 ? fe : fe + 256;           // skip dist_src(256:384)/h_r(384:512) blocks
  Wt[idx] = msg_W[(size_t)(k * 640 + row) * D_ + d];
}

__global__ __launch_bounds__(256) void k_wt_upd(const float* __restrict__ upd_W,
    float* __restrict__ Wt) {
  int idx = blockIdx.x * 256 + threadIdx.x;     // total L*D*D, layout [k][d][f]
  int f = idx & 127;
  int kd = idx >> 7;
  int d = kd & 127;
  int k = kd >> 7;
  Wt[idx] = upd_W[(size_t)(k * D_ + f) * D_ + d];
}

// ---------------- message GEMM + scatter: per active edge ----------------
// msg = relu( comp@W1 + h_src@W2 + conf@W5 + T3b[dclip[src]] + T4[rel] ); aggr[b,tgt] += msg
__global__ __launch_bounds__(256) void k_msg(
    const int* __restrict__ count_p, const int* __restrict__ list,
    const int* __restrict__ edge_index, const int* __restrict__ rels,
    const int* __restrict__ dists, const float* __restrict__ h,
    const float* __restrict__ rel_table, const float* __restrict__ conf,
    const float* __restrict__ Wt,     // [128][384] this layer (d-major)
    const float* __restrict__ T3b,    // [10][128]
    const float* __restrict__ T4,     // [200][128]
    float* __restrict__ aggr) {
  int cnt = *count_p;
  int base = blockIdx.x * TE;
  if (base >= cnt) return;
  int ne = min(TE, cnt - base);
  __shared__ __align__(16) float sA[TE][KEFF];
  __shared__ int sMeta[TE][5];     // hsrc_row, conf_row(id), aggr_row, dclip, rel
  int tid = threadIdx.x;
  if (tid < ne) {
    int id = list[base + tid];
    int b = id >> 14;              // E = 2^14
    int e = id & (E_ - 1);
    int src = edge_index[(b * 2) * E_ + e];
    int tgt = edge_index[(b * 2 + 1) * E_ + e];
    int dc = dists[b * N_ + src];
    dc = dc < 0 ? 0 : (dc > 9 ? 9 : dc);
    sMeta[tid][0] = b * N_ + src;
    sMeta[tid][1] = id;
    sMeta[tid][2] = b * N_ + tgt;
    sMeta[tid][3] = dc;
    sMeta[tid][4] = rels[id];      // rels is [B][E] flat == id
  }
  __syncthreads();
  // stage: cols [0:128)=h_r (becomes comp), [128:256)=h_src, [256:384)=conf
  for (int s = tid; s < ne * 96; s += 256) {
    int i = s / 96, p = s - i * 96;
    float4 v;
    if (p < 32)      v = *(const float4*)&rel_table[sMeta[i][4] * D_ + p * 4];
    else if (p < 64) v = *(const float4*)&h[(size_t)sMeta[i][0] * D_ + (p - 32) * 4];
    else             v = *(const float4*)&conf[(size_t)sMeta[i][1] * D_ + (p - 64) * 4];
    *(float4*)&sA[i][p * 4] = v;
  }
  __syncthreads();
  for (int s = tid; s < ne * 32; s += 256) {   // comp = h_r * h_src
    int i = s >> 5, p = s & 31;
    float4 a = *(float4*)&sA[i][p * 4];
    float4 b = *(float4*)&sA[i][128 + p * 4];
    a.x *= b.x; a.y *= b.y; a.z *= b.z; a.w *= b.w;
    *(float4*)&sA[i][p * 4] = a;
  }
  __syncthreads();
  int wv = tid >> 6, lane = tid & 63;
  float acc[4][2];
#pragma unroll
  for (int e2 = 0; e2 < 4; ++e2) { acc[e2][0] = 0.f; acc[e2][1] = 0.f; }
  const float4* Wt4 = (const float4*)Wt;       // [128][96 float4]
  int r0 = lane * 96, r1 = (lane + 64) * 96;
  for (int f4 = 0; f4 < 96; ++f4) {
    float4 w0 = Wt4[r0 + f4];
    float4 w1 = Wt4[r1 + f4];
#pragma unroll
    for (int e2 = 0; e2 < 4; ++e2) {
      float4 m = *(const float4*)&sA[wv * 4 + e2][f4 * 4];  // wave-uniform broadcast
      acc[e2][0] = fmaf(m.w, w0.w, fmaf(m.z, w0.z, fmaf(m.y, w0.y, fmaf(m.x, w0.x, acc[e2][0]))));
      acc[e2][1] = fmaf(m.w, w1.w, fmaf(m.z, w1.z, fmaf(m.y, w1.y, fmaf(m.x, w1.x, acc[e2][1]))));
    }
  }
#pragma unroll
  for (int e2 = 0; e2 < 4; ++e2) {
    int i = wv * 4 + e2;
    if (i < ne) {
      int dc = sMeta[i][3], rl = sMeta[i][4], ar = sMeta[i][2];
      float b0 = T3b[dc * D_ + lane]      + T4[rl * D_ + lane];
      float b1 = T3b[dc * D_ + 64 + lane] + T4[rl * D_ + 64 + lane];
      float v0 = fmaxf(acc[e2][0] + b0, 0.f);
      float v1 = fmaxf(acc[e2][1] + b1, 0.f);
      unsafeAtomicAdd(&aggr[(size_t)ar * D_ + lane], v0);
      unsafeAtomicAdd(&aggr[(size_t)ar * D_ + 64 + lane], v1);
    }
  }
}

// ---------------- node update: h = aggr@upd_W + upd_b + h ; aggr = 0 ----------------
__global__ __launch_bounds__(256) void k_upd(
    float* __restrict__ aggr, const float* __restrict__ Wt,   // [128][128] d-major
    const float* __restrict__ upd_b, float* __restrict__ h) {
  int base = blockIdx.x * TE;    // row base over B*N rows
  __shared__ __align__(16) float sR[TE][D_];
  int tid = threadIdx.x;
  for (int s = tid; s < TE * 32; s += 256) {
    int i = s >> 5, p = s & 31;
    size_t gi = (size_t)(base + i) * D_ + p * 4;
    float4 v = *(const float4*)&aggr[gi];
    *(float4*)&sR[i][p * 4] = v;
    *(float4*)&aggr[gi] = make_float4(0.f, 0.f, 0.f, 0.f);  // re-zero for next layer
  }
  __syncthreads();
  int wv = tid >> 6, lane = tid & 63;
  float acc[4][2];
#pragma unroll
  for (int e2 = 0; e2 < 4; ++e2) { acc[e2][0] = 0.f; acc[e2][1] = 0.f; }
  const float4* Wt4 = (const float4*)Wt;    // [128][32 float4]
  int r0 = lane * 32, r1 = (lane + 64) * 32;
  for (int f4 = 0; f4 < 32; ++f4) {
    float4 w0 = Wt4[r0 + f4];
    float4 w1 = Wt4[r1 + f4];
#pragma unroll
    for (int e2 = 0; e2 < 4; ++e2) {
      float4 m = *(const float4*)&sR[wv * 4 + e2][f4 * 4];
      acc[e2][0] = fmaf(m.w, w0.w, fmaf(m.z, w0.z, fmaf(m.y, w0.y, fmaf(m.x, w0.x, acc[e2][0]))));
      acc[e2][1] = fmaf(m.w, w1.w, fmaf(m.z, w1.z, fmaf(m.y, w1.y, fmaf(m.x, w1.x, acc[e2][1]))));
    }
  }
#pragma unroll
  for (int e2 = 0; e2 < 4; ++e2) {
    size_t gi = (size_t)(base + wv * 4 + e2) * D_;
    float o0 = acc[e2][0] + upd_b[lane]      + h[gi + lane];
    float o1 = acc[e2][1] + upd_b[64 + lane] + h[gi + 64 + lane];
    h[gi + lane] = o0;
    h[gi + 64 + lane] = o1;
  }
}

// ---------------- final: mask, scores, softmax, top-20, outputs ----------------
__global__ __launch_bounds__(1024) void k_final(
    const float* __restrict__ h, const int* __restrict__ node_mask,
    const float* __restrict__ r_query, const float* __restrict__ att_W,
    const float* __restrict__ att_b, float* __restrict__ out) {
  int b = blockIdx.x;
  int tid = threadIdx.x, lane = tid & 63, wv = tid >> 6;
  __shared__ float sS[N_];
  __shared__ float sRed[1024];
  __shared__ int sRedI[1024];
  __shared__ float sTopV[M_];
  __shared__ int sTopI[M_];
  __shared__ float sCb, sMax, sSum;
  if (wv == 0) {   // per-batch constant: r_query[b] . att_W[128:256] + att_b
    float v = r_query[b * D_ + lane] * att_W[D_ + lane]
            + r_query[b * D_ + 64 + lane] * att_W[D_ + 64 + lane];
#pragma unroll
    for (int off = 32; off > 0; off >>= 1) v += __shfl_xor(v, off);
    if (lane == 0) sCb = v + att_b[0];
  }
  __syncthreads();
  float cb = sCb;
  for (int n = wv; n < N_; n += 16) {   // one wave per node
    float s;
    if (node_mask[b * N_ + n] == 0) {
      s = -1e9f;
    } else {
      const float* hp = &h[((size_t)b * N_ + n) * D_];
      float v = hp[lane] * att_W[lane] + hp[64 + lane] * att_W[64 + lane];
#pragma unroll
      for (int off = 32; off > 0; off >>= 1) v += __shfl_xor(v, off);
      s = v + cb;
      s = s > 0.f ? s : 0.01f * s;      // leaky_relu(0.01)
    }
    if (lane == 0) sS[n] = s;
  }
  __syncthreads();
  // block max
  float lm = -INFINITY;
  for (int n = tid; n < N_; n += 1024) lm = fmaxf(lm, sS[n]);
  sRed[tid] = lm;
  __syncthreads();
  for (int st = 512; st > 0; st >>= 1) {
    if (tid < st) sRed[tid] = fmaxf(sRed[tid], sRed[tid + st]);
    __syncthreads();
  }
  if (tid == 0) sMax = sRed[0];
  __syncthreads();
  float mx = sMax;
  // softmax denom
  float ls = 0.f;
  for (int n = tid; n < N_; n += 1024) ls += expf(sS[n] - mx);
  sRed[tid] = ls;
  __syncthreads();
  for (int st = 512; st > 0; st >>= 1) {
    if (tid < st) sRed[tid] += sRed[tid + st];
    __syncthreads();
  }
  if (tid == 0) sSum = sRed[0];
  __syncthreads();
  float sum = sSum;
  // top-20 by repeated argmax (ties -> lowest index, matches lax.top_k)
  for (int j = 0; j < M_; ++j) {
    float bv = -INFINITY; int bi = N_;
    for (int n = tid; n < N_; n += 1024) {
      float v = sS[n];
      if (v > bv) { bv = v; bi = n; }   // ascending scan keeps lowest index on ties
    }
    sRed[tid] = bv; sRedI[tid] = bi;
    __syncthreads();
    for (int st = 512; st > 0; st >>= 1) {
      if (tid < st) {
        float v2 = sRed[tid + st]; int i2 = sRedI[tid + st];
        if (v2 > sRed[tid] || (v2 == sRed[tid] && i2 < sRedI[tid])) {
          sRed[tid] = v2; sRedI[tid] = i2;
        }
      }
      __syncthreads();
    }
    if (tid == 0) { sTopV[j] = sRed[0]; sTopI[j] = sRedI[0]; sS[sRedI[0]] = -INFINITY; }
    __syncthreads();
  }
  // t_state = (h * mask)[b,0,:]
  if (tid < D_) {
    float v = node_mask[b * N_] ? h[(size_t)b * N_ * D_ + tid] : 0.f;
    out[B_ * M_ * D_ + b * D_ + tid] = v;
  }
  // H_evd[b,j,:] = h[b,idx_j,:]*mask * alpha_j
  for (int s = tid; s < M_ * D_; s += 1024) {
    int j = s >> 7, d = s & 127;
    int idx = sTopI[j];
    float alpha = expf(sTopV[j] - mx) / sum;
    float hv = h[((size_t)b * N_ + idx) * D_ + d];
    if (!node_mask[b * N_ + idx]) hv = 0.f;
    out[(b * M_ + j) * D_ + d] = hv * alpha;
  }
}

// ---------------- host ----------------
extern "C" void kernel_launch(void* const* d_in, const int* in_sizes, int n_in,
                              void* d_out, int out_size, void* d_ws, size_t ws_size,
                              hipStream_t stream) {
  const int*   dists      = (const int*)d_in[0];
  const int*   edge_index = (const int*)d_in[1];
  const int*   rels       = (const int*)d_in[2];
  const int*   node_mask  = (const int*)d_in[3];
  const int*   edge_mask  = (const int*)d_in[4];
  const float* r_query    = (const float*)d_in[5];
  const float* conf       = (const float*)d_in[6];
  const float* noise      = (const float*)d_in[7];
  const float* dist_table = (const float*)d_in[8];
  const float* rel_table  = (const float*)d_in[9];
  const float* msg_W      = (const float*)d_in[10];
  const float* msg_b      = (const float*)d_in[11];
  const float* upd_W      = (const float*)d_in[12];
  const float* upd_b      = (const float*)d_in[13];
  const float* att_W      = (const float*)d_in[14];
  const float* att_b      = (const float*)d_in[15];
  float* out = (float*)d_out;

  char* ws = (char*)d_ws;
  size_t off = 0;
  auto alloc = [&](size_t bytes) {
    void* p = ws + off;
    off = (off + bytes + 255) & ~(size_t)255;
    return p;
  };
  int*   count  = (int*)alloc(4);
  int*   list   = (int*)alloc((size_t)B_ * E_ * 4);
  float* h      = (float*)alloc((size_t)B_ * N_ * D_ * 4);
  float* aggr   = (float*)alloc((size_t)B_ * N_ * D_ * 4);
  float* Wt_msg = (float*)alloc((size_t)L_ * D_ * KEFF * 4);
  float* Wt_upd = (float*)alloc((size_t)L_ * D_ * D_ * 4);
  float* T3b    = (float*)alloc((size_t)L_ * 10 * D_ * 4);
  float* T4     = (float*)alloc((size_t)L_ * R_ * D_ * 4);
  (void)ws_size; (void)in_sizes; (void)n_in; (void)out_size;

  hipMemsetAsync(count, 0, 4, stream);
  hipMemsetAsync(aggr, 0, (size_t)B_ * N_ * D_ * 4, stream);

  k_init_h<<<B_ * N_ * D_ / 4 / 256, 256, 0, stream>>>(dists, noise, dist_table, h);
  k_compact<<<B_ * E_ / 256, 256, 0, stream>>>(edge_mask, count, list);
  k_tables<<<L_ * 210, 128, 0, stream>>>(dist_table, rel_table, msg_W, msg_b, T3b, T4);
  k_wt_msg<<<L_ * D_ * KEFF / 256, 256, 0, stream>>>(msg_W, Wt_msg);
  k_wt_upd<<<L_ * D_ * D_ / 256, 256, 0, stream>>>(upd_W, Wt_upd);

  for (int k = 0; k < L_; ++k) {
    k_msg<<<B_ * E_ / TE, 256, 0, stream>>>(count, list, edge_index, rels, dists, h,
        rel_table, conf, Wt_msg + (size_t)k * D_ * KEFF,
        T3b + k * 10 * D_, T4 + k * R_ * D_, aggr);
    k_upd<<<B_ * N_ / TE, 256, 0, stream>>>(aggr, Wt_upd + (size_t)k * D_ * D_,
        upd_b + k * D_, h);
  }
  k_final<<<B_, 1024, 0, stream>>>(h, node_mask, r_query, att_W, att_b, out);
}

// Round 3
// 475.056 us; speedup vs baseline: 4.3832x; 4.3832x over previous
//
#include <hip/hip_runtime.h>
#include <hip/hip_bf16.h>
#include <math.h>

#define B_ 8
#define N_ 8192
#define E_ 16384
#define D_ 128
#define R_ 200
#define M_ 20
#define L_ 3
#define KEFF 384   // comp(128) + h_src(128) + conf(128); dist/rel blocks folded into tables

typedef __attribute__((ext_vector_type(8))) short bf16x8;
typedef __attribute__((ext_vector_type(4))) float f32x4;

__device__ __forceinline__ short f2b(float f) {
  union { __hip_bfloat16 b; short s; } u;
  u.b = __float2bfloat16(f);
  return u.s;
}

// ---------------- h init: h = dist_table[clip(dists)] + 0.1*noise ----------------
__global__ __launch_bounds__(256) void k_init_h(const int* __restrict__ dists,
    const float* __restrict__ noise, const float* __restrict__ dist_table,
    float* __restrict__ h) {
  int i = blockIdx.x * 256 + threadIdx.x;   // float4 index, total B*N*D/4
  int row = i >> 5;                          // D/4 = 32 float4 per row
  int d4 = i & 31;
  int dc = dists[row]; dc = dc < 0 ? 0 : (dc > 9 ? 9 : dc);
  const float4 t = *(const float4*)&dist_table[dc * D_ + d4 * 4];
  const float4 nz = *(const float4*)&noise[(size_t)i * 4];
  float4 o;
  o.x = t.x + 0.1f * nz.x; o.y = t.y + 0.1f * nz.y;
  o.z = t.z + 0.1f * nz.z; o.w = t.w + 0.1f * nz.w;
  *(float4*)&h[(size_t)i * 4] = o;
}

// ---------------- active-edge compaction ----------------
__global__ __launch_bounds__(256) void k_compact(const int* __restrict__ edge_mask,
    int* __restrict__ count, int* __restrict__ list) {
  int i = blockIdx.x * 256 + threadIdx.x;
  bool act = edge_mask[i] != 0;
  unsigned long long m = __ballot(act);
  int lane = threadIdx.x & 63;
  int base = 0;
  if (lane == 0) base = atomicAdd(count, __popcll(m));
  base = __shfl(base, 0);
  if (act) list[base + __popcll(m & ((1ull << lane) - 1ull))] = i;  // i = b*E+e
}

// ------- T3b[k][t][d] = dist_table[t]@W3[k] + msg_b[k],  T4[k][r][d] = rel_table[r]@W4[k]
__global__ __launch_bounds__(128) void k_tables(const float* __restrict__ dist_table,
    const float* __restrict__ rel_table, const float* __restrict__ msg_W,
    const float* __restrict__ msg_b, float* __restrict__ T3b, float* __restrict__ T4) {
  int k = blockIdx.x / 210;
  int r = blockIdx.x % 210;
  int d = threadIdx.x;
  if (r < 10) {
    float acc = msg_b[k * D_ + d];
    for (int f = 0; f < D_; ++f)
      acc = fmaf(dist_table[r * D_ + f], msg_W[(size_t)(k * 640 + 256 + f) * D_ + d], acc);
    T3b[(k * 10 + r) * D_ + d] = acc;
  } else {
    int rr = r - 10;
    float acc = 0.f;
    for (int f = 0; f < D_; ++f)
      acc = fmaf(rel_table[rr * D_ + f], msg_W[(size_t)(k * 640 + 384 + f) * D_ + d], acc);
    T4[(k * R_ + rr) * D_ + d] = acc;
  }
}

// ------- Wbt_msg[k][n][fe] (bf16): effective msg weight, n-major so B-frags read contiguous
__global__ __launch_bounds__(256) void k_wbt_msg(const float* __restrict__ msg_W,
    short* __restrict__ Wbt) {
  int idx = blockIdx.x * 256 + threadIdx.x;   // L*128*384
  int fe = idx % KEFF;
  int t = idx / KEFF;
  int n = t & 127;
  int k = t >> 7;
  int row = fe < 256 ? fe : fe + 256;         // skip dist(256:384)/rel(384:512) blocks
  Wbt[idx] = f2b(msg_W[(size_t)(k * 640 + row) * D_ + n]);
}

__global__ __launch_bounds__(256) void k_wbt_upd(const float* __restrict__ upd_W,
    short* __restrict__ Wbt) {
  int idx = blockIdx.x * 256 + threadIdx.x;   // L*128*128, layout [k][n][f]
  int f = idx & 127;
  int t = idx >> 7;
  int n = t & 127;
  int k = t >> 7;
  Wbt[idx] = f2b(upd_W[(size_t)(k * D_ + f) * D_ + n]);
}

// ---------------- message GEMM (MFMA) + scatter ----------------
// 64 edges x 128 out per block; K=384 in 6 chunks of 64. 4 waves, each 32x64 tile.
__global__ __launch_bounds__(256) void k_msg(
    const int* __restrict__ count_p, const int* __restrict__ list,
    const int* __restrict__ edge_index, const int* __restrict__ rels,
    const int* __restrict__ dists, const float* __restrict__ h,
    const float* __restrict__ rel_table, const float* __restrict__ conf,
    const short* __restrict__ Wbt,    // [128][384] bf16 (n-major), this layer
    const float* __restrict__ T3b,    // [10][128]
    const float* __restrict__ T4,     // [200][128]
    float* __restrict__ aggr) {
  int cnt = *count_p;
  int base = blockIdx.x * 64;
  if (base >= cnt) return;
  int ne = min(64, cnt - base);
  __shared__ __align__(16) short sA[64][72];   // 144B stride: 16B-aligned rows, near-floor banks
  __shared__ __align__(16) short sB[128][72];
  __shared__ int sMeta[64][5];                 // hsrc_row, id(conf row), aggr_row, dclip, rel
  int tid = threadIdx.x;
  if (tid < 64) {
    if (tid < ne) {
      int id = list[base + tid];
      int b = id >> 14;                        // E = 2^14
      int e = id & (E_ - 1);
      int src = edge_index[(b * 2) * E_ + e];
      int tgt = edge_index[(b * 2 + 1) * E_ + e];
      int dc = dists[b * N_ + src];
      dc = dc < 0 ? 0 : (dc > 9 ? 9 : dc);
      sMeta[tid][0] = b * N_ + src;
      sMeta[tid][1] = id;
      sMeta[tid][2] = b * N_ + tgt;
      sMeta[tid][3] = dc;
      sMeta[tid][4] = rels[id];
    } else {
      sMeta[tid][0] = 0; sMeta[tid][1] = 0; sMeta[tid][2] = 0;
      sMeta[tid][3] = 0; sMeta[tid][4] = 0;
    }
  }
  __syncthreads();
  int lane = tid & 63, wv = tid >> 6;
  int wm = wv >> 1, wn = wv & 1;               // wave tile: rows [wm*32,+32), cols [wn*64,+64)
  int g = lane >> 4, cl = lane & 15;
  f32x4 acc[2][4];
  f32x4 zz = {0.f, 0.f, 0.f, 0.f};
#pragma unroll
  for (int tm = 0; tm < 2; ++tm)
#pragma unroll
    for (int tn = 0; tn < 4; ++tn) acc[tm][tn] = zz;
  int si = tid >> 2, sq = tid & 3;             // A staging: edge si, quarter sq
  int nB = tid >> 1, hB = tid & 1;             // B staging: out-col nB, half hB
  for (int kc = 0; kc < 6; ++kc) {
    // ---- stage A chunk (fp32 sources -> bf16) ----
    float v[16];
    if (si < ne) {
      int c0 = kc * 64 + sq * 16;
      if (kc < 2) {            // comp = h[src] * rel_table[rel]
        const float4* hp = (const float4*)&h[(size_t)sMeta[si][0] * D_ + c0];
        const float4* rp = (const float4*)&rel_table[sMeta[si][4] * D_ + c0];
#pragma unroll
        for (int j = 0; j < 4; ++j) {
          float4 a = hp[j], r = rp[j];
          v[4*j] = a.x*r.x; v[4*j+1] = a.y*r.y; v[4*j+2] = a.z*r.z; v[4*j+3] = a.w*r.w;
        }
      } else if (kc < 4) {     // h_src
        const float4* hp = (const float4*)&h[(size_t)sMeta[si][0] * D_ + (c0 - 128)];
#pragma unroll
        for (int j = 0; j < 4; ++j) {
          float4 a = hp[j];
          v[4*j] = a.x; v[4*j+1] = a.y; v[4*j+2] = a.z; v[4*j+3] = a.w;
        }
      } else {                 // conf
        const float4* cp = (const float4*)&conf[(size_t)sMeta[si][1] * D_ + (c0 - 256)];
#pragma unroll
        for (int j = 0; j < 4; ++j) {
          float4 a = cp[j];
          v[4*j] = a.x; v[4*j+1] = a.y; v[4*j+2] = a.z; v[4*j+3] = a.w;
        }
      }
    } else {
#pragma unroll
      for (int j = 0; j < 16; ++j) v[j] = 0.f;
    }
    bf16x8 p0, p1;
#pragma unroll
    for (int j = 0; j < 8; ++j) { p0[j] = f2b(v[j]); p1[j] = f2b(v[j + 8]); }
    *(bf16x8*)&sA[si][sq * 16] = p0;
    *(bf16x8*)&sA[si][sq * 16 + 8] = p1;
    // ---- stage B chunk (bf16 global, dense) ----
    const bf16x8* wp = (const bf16x8*)&Wbt[(size_t)nB * KEFF + kc * 64 + hB * 32];
#pragma unroll
    for (int j = 0; j < 4; ++j) *(bf16x8*)&sB[nB][hB * 32 + j * 8] = wp[j];
    __syncthreads();
    // ---- MFMA: 2 K-steps of 32 ----
#pragma unroll
    for (int ks = 0; ks < 2; ++ks) {
      int co = ks * 32 + g * 8;
      bf16x8 af[2], bfr[4];
      af[0] = *(const bf16x8*)&sA[wm * 32 + cl][co];
      af[1] = *(const bf16x8*)&sA[wm * 32 + 16 + cl][co];
#pragma unroll
      for (int tn = 0; tn < 4; ++tn)
        bfr[tn] = *(const bf16x8*)&sB[wn * 64 + tn * 16 + cl][co];
#pragma unroll
      for (int tm = 0; tm < 2; ++tm)
#pragma unroll
        for (int tn = 0; tn < 4; ++tn)
          acc[tm][tn] = __builtin_amdgcn_mfma_f32_16x16x32_bf16(af[tm], bfr[tn], acc[tm][tn], 0, 0, 0);
    }
    __syncthreads();
  }
  // ---- epilogue: bias + relu + atomic scatter ----
#pragma unroll
  for (int tm = 0; tm < 2; ++tm)
#pragma unroll
    for (int reg = 0; reg < 4; ++reg) {
      int edge = wm * 32 + tm * 16 + g * 4 + reg;   // C/D: row=(lane>>4)*4+reg, col=lane&15
      if (edge < ne) {
        int arow = sMeta[edge][2];
        int dc = sMeta[edge][3];
        int rl = sMeta[edge][4];
#pragma unroll
        for (int tn = 0; tn < 4; ++tn) {
          int n = wn * 64 + tn * 16 + cl;
          float bias = T3b[dc * D_ + n] + T4[rl * D_ + n];
          float vv = fmaxf(acc[tm][tn][reg] + bias, 0.f);
          unsafeAtomicAdd(&aggr[(size_t)arow * D_ + n], vv);
        }
      }
    }
}

// ---------------- node update (MFMA): h = aggr@upd_W + upd_b + h ; aggr = 0 ----------------
__global__ __launch_bounds__(256) void k_upd(
    float* __restrict__ aggr, const short* __restrict__ Wbt,   // [128][128] bf16 n-major
    const float* __restrict__ upd_b, float* __restrict__ h) {
  int base = blockIdx.x * 64;
  __shared__ __align__(16) short sA[64][72];
  __shared__ __align__(16) short sB[128][72];
  int tid = threadIdx.x;
  int lane = tid & 63, wv = tid >> 6;
  int wm = wv >> 1, wn = wv & 1;
  int g = lane >> 4, cl = lane & 15;
  f32x4 acc[2][4];
  f32x4 zz = {0.f, 0.f, 0.f, 0.f};
#pragma unroll
  for (int tm = 0; tm < 2; ++tm)
#pragma unroll
    for (int tn = 0; tn < 4; ++tn) acc[tm][tn] = zz;
  int si = tid >> 2, sq = tid & 3;
  int nB = tid >> 1, hB = tid & 1;
  for (int kc = 0; kc < 2; ++kc) {
    float4* ap = (float4*)&aggr[(size_t)(base + si) * D_ + kc * 64 + sq * 16];
    float v[16];
    float4 z4 = make_float4(0.f, 0.f, 0.f, 0.f);
#pragma unroll
    for (int j = 0; j < 4; ++j) {
      float4 a = ap[j];
      ap[j] = z4;                               // re-zero for next layer
      v[4*j] = a.x; v[4*j+1] = a.y; v[4*j+2] = a.z; v[4*j+3] = a.w;
    }
    bf16x8 p0, p1;
#pragma unroll
    for (int j = 0; j < 8; ++j) { p0[j] = f2b(v[j]); p1[j] = f2b(v[j + 8]); }
    *(bf16x8*)&sA[si][sq * 16] = p0;
    *(bf16x8*)&sA[si][sq * 16 + 8] = p1;
    const bf16x8* wp = (const bf16x8*)&Wbt[(size_t)nB * D_ + kc * 64 + hB * 32];
#pragma unroll
    for (int j = 0; j < 4; ++j) *(bf16x8*)&sB[nB][hB * 32 + j * 8] = wp[j];
    __syncthreads();
#pragma unroll
    for (int ks = 0; ks < 2; ++ks) {
      int co = ks * 32 + g * 8;
      bf16x8 af[2], bfr[4];
      af[0] = *(const bf16x8*)&sA[wm * 32 + cl][co];
      af[1] = *(const bf16x8*)&sA[wm * 32 + 16 + cl][co];
#pragma unroll
      for (int tn = 0; tn < 4; ++tn)
        bfr[tn] = *(const bf16x8*)&sB[wn * 64 + tn * 16 + cl][co];
#pragma unroll
      for (int tm = 0; tm < 2; ++tm)
#pragma unroll
        for (int tn = 0; tn < 4; ++tn)
          acc[tm][tn] = __builtin_amdgcn_mfma_f32_16x16x32_bf16(af[tm], bfr[tn], acc[tm][tn], 0, 0, 0);
    }
    __syncthreads();
  }
#pragma unroll
  for (int tm = 0; tm < 2; ++tm)
#pragma unroll
    for (int reg = 0; reg < 4; ++reg) {
      int grow = base + wm * 32 + tm * 16 + g * 4 + reg;
#pragma unroll
      for (int tn = 0; tn < 4; ++tn) {
        int n = wn * 64 + tn * 16 + cl;
        size_t gi = (size_t)grow * D_ + n;
        h[gi] = acc[tm][tn][reg] + upd_b[n] + h[gi];
      }
    }
}

// ---------------- scores: one wave per node, full att_in dot ----------------
__global__ __launch_bounds__(256) void k_score(const float* __restrict__ h,
    const int* __restrict__ node_mask, const float* __restrict__ r_query,
    const float* __restrict__ att_W, const float* __restrict__ att_b,
    float* __restrict__ sSg) {
  int wv = threadIdx.x >> 6, lane = threadIdx.x & 63;
  int node = blockIdx.x * 4 + wv;              // [0, B*N)
  int b = node >> 13;                           // N = 2^13
  float s;
  if (node_mask[node] == 0) {
    s = -1e9f;
  } else {
    float2 hv = *(const float2*)&h[(size_t)node * D_ + lane * 2];
    float2 w0 = *(const float2*)&att_W[lane * 2];
    float2 w1 = *(const float2*)&att_W[D_ + lane * 2];
    float2 rq = *(const float2*)&r_query[b * D_ + lane * 2];
    float v = hv.x * w0.x + hv.y * w0.y + rq.x * w1.x + rq.y * w1.y;
#pragma unroll
    for (int off = 32; off > 0; off >>= 1) v += __shfl_xor(v, off);
    v += att_b[0];
    s = v > 0.f ? v : 0.01f * v;
  }
  if (lane == 0) sSg[node] = s;
}

// ---------------- per-batch: softmax stats + top-20 + outputs ----------------
__global__ __launch_bounds__(1024) void k_top(const float* __restrict__ sSg,
    const float* __restrict__ h, const int* __restrict__ node_mask,
    float* __restrict__ out) {
  int b = blockIdx.x;
  int tid = threadIdx.x, lane = tid & 63, wv = tid >> 6;   // 16 waves
  __shared__ float sS[N_];
  __shared__ float sRw[16];
  __shared__ float sSegV[16];
  __shared__ int sSegI[16];
  __shared__ float sTopV[M_];
  __shared__ int sTopI[M_];
  __shared__ float sMax, sSum;
  const float4* gp = (const float4*)&sSg[(size_t)b * N_];
#pragma unroll
  for (int r = 0; r < 2; ++r) {
    float4 x = gp[tid + r * 1024];
    *(float4*)&sS[(tid + r * 1024) * 4] = x;
  }
  __syncthreads();
  // block max
  float lm = -INFINITY;
  for (int n = tid; n < N_; n += 1024) lm = fmaxf(lm, sS[n]);
#pragma unroll
  for (int off = 32; off > 0; off >>= 1) lm = fmaxf(lm, __shfl_xor(lm, off));
  if (lane == 0) sRw[wv] = lm;
  __syncthreads();
  if (tid == 0) {
    float m = sRw[0];
    for (int i = 1; i < 16; ++i) m = fmaxf(m, sRw[i]);
    sMax = m;
  }
  __syncthreads();
  float mx = sMax;
  // softmax denom
  float ls = 0.f;
  for (int n = tid; n < N_; n += 1024) ls += expf(sS[n] - mx);
#pragma unroll
  for (int off = 32; off > 0; off >>= 1) ls += __shfl_xor(ls, off);
  if (lane == 0) sRw[wv] = ls;
  __syncthreads();
  if (tid == 0) {
    float s = 0.f;
    for (int i = 0; i < 16; ++i) s += sRw[i];
    sSum = s;
  }
  // per-wave segment argmax (segment = 512 nodes), ties -> lowest index
  {
    float bv = -INFINITY; int bi = 0;
    int s0 = wv * 512;
    for (int t2 = 0; t2 < 8; ++t2) {
      int n = s0 + lane + t2 * 64;
      float x = sS[n];
      if (x > bv) { bv = x; bi = n; }
    }
#pragma unroll
    for (int off = 32; off > 0; off >>= 1) {
      float vv = __shfl_xor(bv, off); int ii = __shfl_xor(bi, off);
      if (vv > bv || (vv == bv && ii < bi)) { bv = vv; bi = ii; }
    }
    if (lane == 0) { sSegV[wv] = bv; sSegI[wv] = bi; }
  }
  __syncthreads();
  // top-20: pick best segment, knock out, rescan only that segment
  for (int j = 0; j < M_; ++j) {
    if (wv == 0) {
      float bv = (lane < 16) ? sSegV[lane] : -INFINITY;
      int bi = (lane < 16) ? sSegI[lane] : 0x7fffffff;
#pragma unroll
      for (int off = 32; off > 0; off >>= 1) {
        float vv = __shfl_xor(bv, off); int ii = __shfl_xor(bi, off);
        if (vv > bv || (vv == bv && ii < bi)) { bv = vv; bi = ii; }
      }
      if (lane == 0) { sTopV[j] = bv; sTopI[j] = bi; sS[bi] = -INFINITY; }
    }
    __syncthreads();
    int seg = sTopI[j] >> 9;
    if (wv == seg) {
      float bv = -INFINITY; int bi = 0;
      int s0 = wv * 512;
      for (int t2 = 0; t2 < 8; ++t2) {
        int n = s0 + lane + t2 * 64;
        float x = sS[n];
        if (x > bv) { bv = x; bi = n; }
      }
#pragma unroll
      for (int off = 32; off > 0; off >>= 1) {
        float vv = __shfl_xor(bv, off); int ii = __shfl_xor(bi, off);
        if (vv > bv || (vv == bv && ii < bi)) { bv = vv; bi = ii; }
      }
      if (lane == 0) { sSegV[wv] = bv; sSegI[wv] = bi; }
    }
    __syncthreads();
  }
  float sum = sSum;
  // t_state = (h*mask)[b,0,:]
  if (tid < D_) {
    float vv = node_mask[b * N_] ? h[(size_t)b * N_ * D_ + tid] : 0.f;
    out[B_ * M_ * D_ + b * D_ + tid] = vv;
  }
  // H_evd[b,j,:] = (h*mask)[b,idx_j,:] * alpha_j
  for (int s2 = tid; s2 < M_ * D_; s2 += 1024) {
    int j = s2 >> 7, d = s2 & 127;
    int idx = sTopI[j];
    float alpha = expf(sTopV[j] - mx) / sum;
    float hv = h[((size_t)b * N_ + idx) * D_ + d];
    if (!node_mask[b * N_ + idx]) hv = 0.f;
    out[(b * M_ + j) * D_ + d] = hv * alpha;
  }
}

// ---------------- host ----------------
extern "C" void kernel_launch(void* const* d_in, const int* in_sizes, int n_in,
                              void* d_out, int out_size, void* d_ws, size_t ws_size,
                              hipStream_t stream) {
  const int*   dists      = (const int*)d_in[0];
  const int*   edge_index = (const int*)d_in[1];
  const int*   rels       = (const int*)d_in[2];
  const int*   node_mask  = (const int*)d_in[3];
  const int*   edge_mask  = (const int*)d_in[4];
  const float* r_query    = (const float*)d_in[5];
  const float* conf       = (const float*)d_in[6];
  const float* noise      = (const float*)d_in[7];
  const float* dist_table = (const float*)d_in[8];
  const float* rel_table  = (const float*)d_in[9];
  const float* msg_W      = (const float*)d_in[10];
  const float* msg_b      = (const float*)d_in[11];
  const float* upd_W      = (const float*)d_in[12];
  const float* upd_b      = (const float*)d_in[13];
  const float* att_W      = (const float*)d_in[14];
  const float* att_b      = (const float*)d_in[15];
  float* out = (float*)d_out;

  char* ws = (char*)d_ws;
  size_t off = 0;
  auto alloc = [&](size_t bytes) {
    void* p = ws + off;
    off = (off + bytes + 255) & ~(size_t)255;
    return p;
  };
  int*   count   = (int*)alloc(4);
  int*   list    = (int*)alloc((size_t)B_ * E_ * 4);
  float* h       = (float*)alloc((size_t)B_ * N_ * D_ * 4);
  float* aggr    = (float*)alloc((size_t)B_ * N_ * D_ * 4);
  short* Wbt_msg = (short*)alloc((size_t)L_ * D_ * KEFF * 2);
  short* Wbt_upd = (short*)alloc((size_t)L_ * D_ * D_ * 2);
  float* T3b     = (float*)alloc((size_t)L_ * 10 * D_ * 4);
  float* T4      = (float*)alloc((size_t)L_ * R_ * D_ * 4);
  float* scores  = (float*)alloc((size_t)B_ * N_ * 4);
  (void)ws_size; (void)in_sizes; (void)n_in; (void)out_size;

  hipMemsetAsync(count, 0, 4, stream);
  hipMemsetAsync(aggr, 0, (size_t)B_ * N_ * D_ * 4, stream);

  k_init_h<<<B_ * N_ * D_ / 4 / 256, 256, 0, stream>>>(dists, noise, dist_table, h);
  k_compact<<<B_ * E_ / 256, 256, 0, stream>>>(edge_mask, count, list);
  k_tables<<<L_ * 210, 128, 0, stream>>>(dist_table, rel_table, msg_W, msg_b, T3b, T4);
  k_wbt_msg<<<L_ * D_ * KEFF / 256, 256, 0, stream>>>(msg_W, Wbt_msg);
  k_wbt_upd<<<L_ * D_ * D_ / 256, 256, 0, stream>>>(upd_W, Wbt_upd);

  for (int k = 0; k < L_; ++k) {
    k_msg<<<B_ * E_ / 64, 256, 0, stream>>>(count, list, edge_index, rels, dists, h,
        rel_table, conf, Wbt_msg + (size_t)k * D_ * KEFF,
        T3b + k * 10 * D_, T4 + k * R_ * D_, aggr);
    k_upd<<<B_ * N_ / 64, 256, 0, stream>>>(aggr, Wbt_upd + (size_t)k * D_ * D_,
        upd_b + k * D_, h);
  }
  k_score<<<B_ * N_ / 4, 256, 0, stream>>>(h, node_mask, r_query, att_W, att_b, scores);
  k_top<<<B_, 1024, 0, stream>>>(scores, h, node_mask, out);
}